// Round 3
// baseline (1585.360 us; speedup 1.0000x reference)
//
#include <hip/hip_runtime.h>
#include <math.h>

#define BATCH 4096
#define TT 48
#define DDIM 59
#define HHID 256
#define RR 16
#define NWG (BATCH/RR)     // 256 workgroups
#define NTHR 512           // 8 waves

typedef _Float16 f16;
typedef _Float16 f16x8 __attribute__((ext_vector_type(8)));
typedef float    f32x4 __attribute__((ext_vector_type(4)));

// ---- output layout (floats) ----
static constexpr size_t N_XIMP   = (size_t)BATCH*TT*DDIM;
static constexpr size_t OFF_LOSS = N_XIMP;
static constexpr size_t OFF_HS   = OFF_LOSS + 1;
static constexpr size_t N_HS     = (size_t)BATCH*TT*HHID;
static constexpr size_t OFF_YOUT = OFF_HS + N_HS;
static constexpr size_t OFF_YSC  = OFF_YOUT + BATCH;
static constexpr size_t OFF_DEC  = OFF_YSC + BATCH;

// ---- f16 weight workspace layout (element offsets from wbase) ----
static constexpr size_t WOFF_GRU  = 0;          // 16 jb * 36 blocks
static constexpr size_t WOFF_DH   = 294912;     // 16 nt * 2 kt
static constexpr size_t WOFF_HIST = 311296;     // 4 nt * 8 kt
static constexpr size_t WOFF_FEAT = 327680;     // 4 nt * 2 kt
static constexpr size_t WOFF_WC   = 331776;     // 4 nt * 4 kt

__device__ __forceinline__ float sigm(float v){ return 1.f/(1.f+expf(-v)); }

// =====================================================================
// decay_factor (fully parallel) — nt loads/stores: pure streaming
// =====================================================================
__global__ __launch_bounds__(256) void decay_kernel(
    const float* __restrict__ deltas, const float* __restrict__ medians,
    const float* __restrict__ wobs_W, const float* __restrict__ wobs_b,
    float* __restrict__ out_decay)
{
  __shared__ float sW[DDIM][60];
  __shared__ float sb[64], smed[64];
  __shared__ float sdd[16][60];
  const int tid = threadIdx.x;
  for (int idx = tid; idx < DDIM*DDIM; idx += 256){
    int e = idx/DDIM, d = idx - e*DDIM;
    sW[e][d] = wobs_W[idx];
  }
  if (tid < DDIM){ sb[tid] = wobs_b[tid]; smed[tid] = medians[tid]; }
  __syncthreads();
  const size_t row0 = (size_t)blockIdx.x * 16;
  for (int idx = tid; idx < 16*DDIM; idx += 256){
    int r = idx/DDIM, d = idx - r*DDIM;
    sdd[r][d] = __builtin_nontemporal_load(&deltas[(row0+r)*DDIM + d]) - smed[d];
  }
  __syncthreads();
  for (int idx = tid; idx < 16*DDIM; idx += 256){
    int r = idx/DDIM, e = idx - r*DDIM;
    float acc = sb[e];
    for (int d = 0; d < DDIM; d++) acc += sdd[r][d]*sW[e][d];
    float dd = sdd[r][e];
    float sg = (dd > 0.f) ? 1.f : ((dd < 0.f) ? -1.f : 0.f);
    float v = 0.5f*(1.f - tanhf(sg*fabsf(acc)));
    __builtin_nontemporal_store(v, &out_decay[(row0+r)*DDIM + e]);
  }
}

// =====================================================================
// Weight conversion: fp32 -> f16 MFMA B-fragment blocks (unchanged)
// =====================================================================
__global__ __launch_bounds__(256) void conv_kernel(
    const float* __restrict__ W_dh, const float* __restrict__ hist_W,
    const float* __restrict__ feat_W, const float* __restrict__ wcomb_W,
    const float* __restrict__ W_ih, const float* __restrict__ W_hh,
    f16* __restrict__ ws)
{
  const int g  = blockIdx.x*4 + (threadIdx.x >> 6);
  const int l  = threadIdx.x & 63;
  const int nl = l & 15;
  const int kh = (l >> 4) * 8;
  f16x8 out;
  if (g < 576){                                   // GRU
    int jb = g/36, s = g - jb*36;
    if (s < 24){                                  // r or z (fused ih+hh)
      int gate = s/12, kt = s - gate*12;
      int row  = gate*256 + jb*16 + nl;
      #pragma unroll
      for (int e = 0; e < 8; e++){
        int k = kt*32 + kh + e;
        float v = (k < 256) ? W_hh[(size_t)row*256 + k]
                : (k < 374) ? W_ih[(size_t)row*118 + (k-256)] : 0.f;
        out[e] = (f16)v;
      }
    } else if (s < 32){                           // n-gate hidden part
      int kt = s - 24, row = 512 + jb*16 + nl;
      #pragma unroll
      for (int e = 0; e < 8; e++){
        int k = kt*32 + kh + e;
        out[e] = (f16)W_hh[(size_t)row*256 + k];
      }
    } else {                                      // n-gate input part
      int kt = s - 32, row = 512 + jb*16 + nl;
      #pragma unroll
      for (int e = 0; e < 8; e++){
        int k = kt*32 + kh + e;
        out[e] = (f16)((k < 118) ? W_ih[(size_t)row*118 + k] : 0.f);
      }
    }
    *(f16x8*)&ws[WOFF_GRU + (size_t)g*512 + l*8] = out;
  } else if (g < 608){                            // gamma_h decay W_dh
    int i = g - 576, nt = i >> 1, kt = i & 1;
    int row = nt*16 + nl;
    #pragma unroll
    for (int e = 0; e < 8; e++){
      int k = kt*32 + kh + e;
      out[e] = (f16)((k < 59) ? W_dh[(size_t)row*59 + k] : 0.f);
    }
    *(f16x8*)&ws[WOFF_DH + (size_t)i*512 + l*8] = out;
  } else if (g < 640){                            // hist_W
    int i = g - 608, nt = i >> 3, kt = i & 7;
    int n = nt*16 + nl;
    #pragma unroll
    for (int e = 0; e < 8; e++){
      int k = kt*32 + kh + e;
      out[e] = (f16)((n < 59) ? hist_W[(size_t)n*256 + k] : 0.f);
    }
    *(f16x8*)&ws[WOFF_HIST + (size_t)i*512 + l*8] = out;
  } else if (g < 648){                            // feat_W (off-diag mask baked in)
    int i = g - 640, nt = i >> 1, kt = i & 1;
    int n = nt*16 + nl;
    #pragma unroll
    for (int e = 0; e < 8; e++){
      int k = kt*32 + kh + e;
      out[e] = (f16)((n < 59 && k < 59 && k != n) ? feat_W[(size_t)n*59 + k] : 0.f);
    }
    *(f16x8*)&ws[WOFF_FEAT + (size_t)i*512 + l*8] = out;
  } else {                                        // wcomb_W
    int i = g - 648, nt = i >> 2, kt = i & 3;
    int n = nt*16 + nl;
    #pragma unroll
    for (int e = 0; e < 8; e++){
      int k = kt*32 + kh + e;
      out[e] = (f16)((n < 59 && k < 118) ? wcomb_W[(size_t)n*118 + k] : 0.f);
    }
    *(f16x8*)&ws[WOFF_WC + (size_t)i*512 + l*8] = out;
  }
}

// =====================================================================
// Sequential scan, MFMA + nt-streaming edition.
// Streaming data (x/mask/deltas in, x_imp/hs out) uses non-temporal
// accesses so the per-XCD L2 stays dedicated to the 680 KB weight set.
// Next step's x/m/d prefetched into registers at the top of each step.
// =====================================================================
__global__ __launch_bounds__(NTHR, 1) void seq_kernel(
    const float* __restrict__ x, const float* __restrict__ mask,
    const float* __restrict__ deltas, const float* __restrict__ h0,
    const float* __restrict__ b_dh, const float* __restrict__ W_dx,
    const float* __restrict__ b_dx, const float* __restrict__ hist_b,
    const float* __restrict__ feat_b, const float* __restrict__ wcomb_b,
    const float* __restrict__ b_ih, const float* __restrict__ b_hh,
    const f16* __restrict__ wb,
    float* __restrict__ out_ximp, float* __restrict__ out_hs,
    float* __restrict__ ws_num, float* __restrict__ ws_den)
{
  __shared__ f16 Acat[16*392];   // [h(256) | x_imp(59) | m(59) | pad]
  __shared__ f16 Ad  [16*72];
  __shared__ f16 Axr [16*72];
  __shared__ f16 Agm [16*136];   // [gamma_x(59) | m(59) | pad]
  __shared__ float ssx[16*60], ssm[16*60], ssd[16*60];
  __shared__ float sxh[16*60], sxu[16*60], sbt[16*60];
  __shared__ float sh [16*260];
  __shared__ float sdiag[64], sbdx[64];
  __shared__ float sredN[8], sredD[8];

  const int tid = threadIdx.x;
  const int w   = tid >> 6;
  const int l   = tid & 63;
  const int nl  = l & 15;
  const int kh  = (l >> 4) * 8;
  const int mq  = (l >> 4) * 4;
  const int row0 = blockIdx.x * RR;

  const f16* Bgru  = wb + WOFF_GRU;
  const f16* Bdh   = wb + WOFF_DH;
  const f16* Bhist = wb + WOFF_HIST;
  const f16* Bfeat = wb + WOFF_FEAT;
  const f16* Bwc   = wb + WOFF_WC;

  // staging indices for this thread (2 strided slots cover 944 elems)
  const int i0 = tid,        r0s = i0/59, d0s = i0 - r0s*59;
  const int i1 = tid + NTHR, r1s = i1/59, d1s = i1 - r1s*59;
  const bool has1 = (i1 < 944);

  if (tid < DDIM){ sdiag[tid] = W_dx[(size_t)tid*DDIM + tid]; sbdx[tid] = b_dx[tid]; }
  for (int idx = tid; idx < 16*18; idx += NTHR){
    int r = idx/18, c = idx - (idx/18)*18;
    Acat[r*392 + 374 + c] = (f16)0.f;
    Agm [r*136 + 118 + c] = (f16)0.f;
  }
  for (int idx = tid; idx < 16*13; idx += NTHR){
    int r = idx/13, c = idx - (idx/13)*13;
    Ad [r*72 + 59 + c] = (f16)0.f;
    Axr[r*72 + 59 + c] = (f16)0.f;
  }
  for (int idx = tid; idx < 16*256; idx += NTHR){
    int r = idx >> 8, j = idx & 255;
    sh[r*260 + j] = h0[(size_t)(row0+r)*HHID + j];
  }

  // prologue prefetch (t = 0)
  float vx0, vm0, vd0, vx1 = 0.f, vm1 = 0.f, vd1 = 0.f;
  {
    size_t g0 = ((size_t)(row0+r0s)*TT + 0)*DDIM + d0s;
    vx0 = __builtin_nontemporal_load(&x[g0]);
    vm0 = __builtin_nontemporal_load(&mask[g0]);
    vd0 = __builtin_nontemporal_load(&deltas[g0]);
    if (has1){
      size_t g1 = ((size_t)(row0+r1s)*TT + 0)*DDIM + d1s;
      vx1 = __builtin_nontemporal_load(&x[g1]);
      vm1 = __builtin_nontemporal_load(&mask[g1]);
      vd1 = __builtin_nontemporal_load(&deltas[g1]);
    }
  }
  __syncthreads();

  for (int t = 0; t < TT; t++){
    // ---- stage prefetched x, m, d into LDS ----
    {
      ssx[r0s*60+d0s] = vx0; ssm[r0s*60+d0s] = vm0; ssd[r0s*60+d0s] = vd0;
      Ad  [r0s*72 +d0s]    = (f16)vd0;
      Agm [r0s*136+59+d0s] = (f16)vm0;
      Acat[r0s*392+315+d0s]= (f16)vm0;
      if (has1){
        ssx[r1s*60+d1s] = vx1; ssm[r1s*60+d1s] = vm1; ssd[r1s*60+d1s] = vd1;
        Ad  [r1s*72 +d1s]    = (f16)vd1;
        Agm [r1s*136+59+d1s] = (f16)vm1;
        Acat[r1s*392+315+d1s]= (f16)vm1;
      }
    }
    __syncthreads();

    // ---- issue next step's loads (hidden under this step's compute) ----
    if (t + 1 < TT){
      size_t g0 = ((size_t)(row0+r0s)*TT + (t+1))*DDIM + d0s;
      vx0 = __builtin_nontemporal_load(&x[g0]);
      vm0 = __builtin_nontemporal_load(&mask[g0]);
      vd0 = __builtin_nontemporal_load(&deltas[g0]);
      if (has1){
        size_t g1 = ((size_t)(row0+r1s)*TT + (t+1))*DDIM + d1s;
        vx1 = __builtin_nontemporal_load(&x[g1]);
        vm1 = __builtin_nontemporal_load(&mask[g1]);
        vd1 = __builtin_nontemporal_load(&deltas[g1]);
      }
    }

    // ---- gamma_h MFMA: h *= exp(-relu(d @ W_dh.T + b)) ----
    #pragma unroll
    for (int ii = 0; ii < 2; ii++){
      int nt = 2*w + ii;
      f32x4 acc = {0.f,0.f,0.f,0.f};
      #pragma unroll
      for (int kt = 0; kt < 2; kt++){
        f16x8 a = *(const f16x8*)&Ad[nl*72 + kt*32 + kh];
        f16x8 b = *(const f16x8*)&Bdh[(size_t)(nt*2+kt)*512 + l*8];
        acc = __builtin_amdgcn_mfma_f32_16x16x32_f16(a, b, acc, 0, 0, 0);
      }
      int n = nt*16 + nl;
      float bn = b_dh[n];
      #pragma unroll
      for (int q = 0; q < 4; q++){
        int m = mq + q;
        float gm = expf(-fmaxf(acc[q] + bn, 0.f));
        float hv = sh[m*260 + n] * gm;
        sh[m*260 + n] = hv;
        Acat[m*392 + n] = (f16)hv;
      }
    }
    __syncthreads();

    // ---- x_h MFMA (waves 0-3) || gamma_x VALU (waves 4-7) ----
    if (w < 4){
      int nt = w;
      f32x4 acc = {0.f,0.f,0.f,0.f};
      #pragma unroll
      for (int kt = 0; kt < 8; kt++){
        f16x8 a = *(const f16x8*)&Acat[nl*392 + kt*32 + kh];
        f16x8 b = *(const f16x8*)&Bhist[(size_t)(nt*8+kt)*512 + l*8];
        acc = __builtin_amdgcn_mfma_f32_16x16x32_f16(a, b, acc, 0, 0, 0);
      }
      int n = nt*16 + nl;
      if (n < DDIM){
        float hb = hist_b[n];
        #pragma unroll
        for (int q = 0; q < 4; q++) sxh[(mq+q)*60 + n] = acc[q] + hb;
      }
    } else {
      for (int idx = tid - 256; idx < 944; idx += 256){
        int r = idx/59, d = idx - r*59;
        float gx = expf(-fmaxf(ssd[r*60+d]*sdiag[d] + sbdx[d], 0.f));
        Agm[r*136 + d] = (f16)gx;
      }
    }
    __syncthreads();

    // ---- x_r ----
    for (int idx = tid; idx < 944; idx += NTHR){
      int r = idx/59, d = idx - r*59;
      float m = ssm[r*60+d];
      float xr = m*ssx[r*60+d] + (1.f-m)*sxh[r*60+d];
      Axr[r*72+d] = (f16)xr;
    }
    __syncthreads();

    // ---- feat MFMA (waves 0-3) || beta MFMA (waves 4-7) ----
    if (w < 4){
      int nt = w;
      f32x4 acc = {0.f,0.f,0.f,0.f};
      #pragma unroll
      for (int kt = 0; kt < 2; kt++){
        f16x8 a = *(const f16x8*)&Axr[nl*72 + kt*32 + kh];
        f16x8 b = *(const f16x8*)&Bfeat[(size_t)(nt*2+kt)*512 + l*8];
        acc = __builtin_amdgcn_mfma_f32_16x16x32_f16(a, b, acc, 0, 0, 0);
      }
      int n = nt*16 + nl;
      if (n < DDIM){
        float fb = feat_b[n];
        #pragma unroll
        for (int q = 0; q < 4; q++) sxu[(mq+q)*60 + n] = acc[q] + fb;
      }
    } else {
      int nt = w - 4;
      f32x4 acc = {0.f,0.f,0.f,0.f};
      #pragma unroll
      for (int kt = 0; kt < 4; kt++){
        f16x8 a = *(const f16x8*)&Agm[nl*136 + kt*32 + kh];
        f16x8 b = *(const f16x8*)&Bwc[(size_t)(nt*4+kt)*512 + l*8];
        acc = __builtin_amdgcn_mfma_f32_16x16x32_f16(a, b, acc, 0, 0, 0);
      }
      int n = nt*16 + nl;
      if (n < DDIM){
        float cb = wcomb_b[n];
        #pragma unroll
        for (int q = 0; q < 4; q++) sbt[(mq+q)*60 + n] = sigm(acc[q] + cb);
      }
    }
    __syncthreads();

    // ---- x_comb / loss / x_imp (nt store) ----
    float lnum = 0.f, lden = 0.f;
    for (int idx = tid; idx < 944; idx += NTHR){
      int r = idx/59, i = idx - r*59;
      float xh = sxh[r*60+i], xu = sxu[r*60+i], bt = sbt[r*60+i];
      float xc = bt*xu + (1.f-bt)*xh;
      float m = ssm[r*60+i], xv = ssx[r*60+i];
      lnum += fabsf(xv - xc)*m;
      lden += m;
      float xi = m*xv + (1.f-m)*xc;
      Acat[r*392 + 256 + i] = (f16)xi;
      __builtin_nontemporal_store(xi, &out_ximp[((size_t)(row0+r)*TT + t)*DDIM + i]);
    }
    #pragma unroll
    for (int off = 32; off >= 1; off >>= 1){
      lnum += __shfl_xor(lnum, off);
      lden += __shfl_xor(lden, off);
    }
    if (l == 0){ sredN[w] = lnum; sredD[w] = lden; }
    __syncthreads();
    if (tid == 0){
      float a = 0.f, b = 0.f;
      #pragma unroll
      for (int k = 0; k < 8; k++){ a += sredN[k]; b += sredD[k]; }
      atomicAdd(&ws_num[t], a); atomicAdd(&ws_den[t], b);
    }

    // ---- GRU MFMA ----
    #pragma unroll
    for (int jj = 0; jj < 2; jj++){
      int jb = 2*w + jj;
      const f16* Bb = Bgru + (size_t)jb*36*512;
      f32x4 ar  = {0.f,0.f,0.f,0.f};
      f32x4 az  = {0.f,0.f,0.f,0.f};
      f32x4 anh = {0.f,0.f,0.f,0.f};
      f32x4 ani = {0.f,0.f,0.f,0.f};
      #pragma unroll
      for (int kt = 0; kt < 12; kt++){
        f16x8 a  = *(const f16x8*)&Acat[nl*392 + kt*32 + kh];
        f16x8 br = *(const f16x8*)&Bb[(size_t)kt*512 + l*8];
        f16x8 bz = *(const f16x8*)&Bb[(size_t)(12+kt)*512 + l*8];
        ar = __builtin_amdgcn_mfma_f32_16x16x32_f16(a, br, ar, 0, 0, 0);
        az = __builtin_amdgcn_mfma_f32_16x16x32_f16(a, bz, az, 0, 0, 0);
        if (kt < 8){
          f16x8 bn = *(const f16x8*)&Bb[(size_t)(24+kt)*512 + l*8];
          anh = __builtin_amdgcn_mfma_f32_16x16x32_f16(a, bn, anh, 0, 0, 0);
        } else {
          f16x8 bn = *(const f16x8*)&Bb[(size_t)(32+kt-8)*512 + l*8];
          ani = __builtin_amdgcn_mfma_f32_16x16x32_f16(a, bn, ani, 0, 0, 0);
        }
      }
      int j = jb*16 + nl;
      float br_ = b_ih[j]       + b_hh[j];
      float bz_ = b_ih[256+j]   + b_hh[256+j];
      float bni = b_ih[512+j];
      float bnh = b_hh[512+j];
      #pragma unroll
      for (int q = 0; q < 4; q++){
        int m = mq + q;
        float rg = sigm(ar[q] + br_);
        float zg = sigm(az[q] + bz_);
        float ng = tanhf(ani[q] + bni + rg*(anh[q] + bnh));
        float hold = sh[m*260 + j];
        float hn = (1.f-zg)*ng + zg*hold;
        sh[m*260 + j] = hn;
        __builtin_nontemporal_store(hn, &out_hs[((size_t)(row0+m)*TT + t)*HHID + j]);
      }
    }
    __syncthreads();
  }
}

// =====================================================================
// finalize: x_loss and classification head
// =====================================================================
__global__ __launch_bounds__(256) void final_kernel(
    const float* __restrict__ hs, const float* __restrict__ cls_W,
    const float* __restrict__ cls_b, const float* __restrict__ ws_num,
    const float* __restrict__ ws_den, float* __restrict__ out)
{
  int b = blockIdx.x*256 + threadIdx.x;
  if (b < BATCH){
    const float* hr = hs + ((size_t)b*TT + (TT-1))*HHID;
    float acc = cls_b[0];
    for (int j = 0; j < HHID; j++) acc += hr[j]*cls_W[j];
    out[OFF_YOUT + b] = acc;
    out[OFF_YSC  + b] = sigm(acc);
  }
  if (blockIdx.x == 0 && threadIdx.x == 0){
    float s = 0.f;
    for (int tt = 0; tt < TT; tt++) s += ws_num[tt]/(ws_den[tt] + 1e-5f);
    out[OFF_LOSS] = s;
  }
}

extern "C" void kernel_launch(void* const* d_in, const int* in_sizes, int n_in,
                              void* d_out, int out_size, void* d_ws, size_t ws_size,
                              hipStream_t stream)
{
  const float* x       = (const float*)d_in[0];
  const float* mask_   = (const float*)d_in[1];
  const float* deltas  = (const float*)d_in[2];
  const float* h0      = (const float*)d_in[4];
  const float* medians = (const float*)d_in[5];
  const float* W_dh    = (const float*)d_in[6];
  const float* b_dh    = (const float*)d_in[7];
  const float* W_dx    = (const float*)d_in[8];
  const float* b_dx    = (const float*)d_in[9];
  const float* hist_W  = (const float*)d_in[10];
  const float* hist_b  = (const float*)d_in[11];
  const float* feat_W  = (const float*)d_in[12];
  const float* feat_b  = (const float*)d_in[13];
  const float* wcomb_W = (const float*)d_in[14];
  const float* wcomb_b = (const float*)d_in[15];
  const float* wobs_W  = (const float*)d_in[16];
  const float* wobs_b  = (const float*)d_in[17];
  const float* W_ih    = (const float*)d_in[18];
  const float* W_hh    = (const float*)d_in[19];
  const float* b_ih    = (const float*)d_in[20];
  const float* b_hh    = (const float*)d_in[21];
  const float* cls_W   = (const float*)d_in[22];
  const float* cls_b   = (const float*)d_in[23];

  float* out    = (float*)d_out;
  float* ws_num = (float*)d_ws;              // 48 floats
  float* ws_den = ws_num + TT;               // 48 floats
  f16*   wbase  = (f16*)((char*)d_ws + 512); // f16 weight blocks

  hipMemsetAsync(d_ws, 0, 512, stream);

  conv_kernel<<<166, 256, 0, stream>>>(W_dh, hist_W, feat_W, wcomb_W,
                                       W_ih, W_hh, wbase);

  decay_kernel<<<BATCH*TT/16, 256, 0, stream>>>(deltas, medians, wobs_W, wobs_b,
                                                out + OFF_DEC);

  seq_kernel<<<NWG, NTHR, 0, stream>>>(x, mask_, deltas, h0,
      b_dh, W_dx, b_dx, hist_b, feat_b, wcomb_b, b_ih, b_hh, wbase,
      out /*x_imp*/, out + OFF_HS, ws_num, ws_den);

  final_kernel<<<BATCH/256, 256, 0, stream>>>(out + OFF_HS, cls_W, cls_b,
                                              ws_num, ws_den, out);
}